// Round 2
// baseline (1038.197 us; speedup 1.0000x reference)
//
#include <hip/hip_runtime.h>
#include <hip/hip_bf16.h>
#include <hip/hip_fp16.h>

// B=1024, T=512, H=128, G=4H=512, IN=1
#define TT 512
#define RR 16   // rows per block

using f16   = _Float16;
using f16x8 = __attribute__((ext_vector_type(8))) _Float16;
using f32x4 = __attribute__((ext_vector_type(4))) float;

__device__ __forceinline__ float fast_rcp(float x) { return __builtin_amdgcn_rcpf(x); }
__device__ __forceinline__ float sigm(float x)     { return fast_rcp(1.0f + __expf(-x)); }
__device__ __forceinline__ float tanhf_(float x)   { return 1.0f - 2.0f * fast_rcp(1.0f + __expf(2.0f * x)); }

// LDS layout (dynamic, 147456 B):
//   [0, 131072)        Whh1 as f16, row-major [512][128], XOR-swizzled
//   [131072, 147456)   h1[2], h2[2] f16 buffers, each [16][256B], swizzled
__global__ __launch_bounds__(512, 2) void lstm2_fused(
    const float* __restrict__ x,
    const float* __restrict__ Wih1,
    const float* __restrict__ Whh1,
    const float* __restrict__ bih1,
    const float* __restrict__ bhh1,
    const float* __restrict__ Wih2,
    const float* __restrict__ Whh2,
    const float* __restrict__ bih2,
    const float* __restrict__ bhh2,
    const float* __restrict__ Wl,
    const float* __restrict__ bl,
    float* __restrict__ out)
{
    extern __shared__ char smem[];

    const int tid  = threadIdx.x;
    const int w    = tid >> 6;      // wave 0..7 -> h-dim slice [16w,16w+16)
    const int lane = tid & 63;
    const int r    = lane & 15;     // MFMA row/col index within tile
    const int q    = lane >> 4;     // MFMA k-group / row-group
    const int rowbase = blockIdx.x * RR;

    // ---- stage Whh1 -> LDS f16 (swizzled) ----
    for (int it = 0; it < 64; ++it) {
        int pp = tid + it * 512;           // pair index 0..32767
        int n  = pp >> 6;                  // gate row 0..511
        int kp = pp & 63;                  // k-pair 0..63
        float2 v = *(const float2*)(Whh1 + n * 128 + kp * 2);
        union { f16 h[2]; unsigned u; } cv;
        cv.h[0] = (f16)v.x; cv.h[1] = (f16)v.y;
        int off = n * 256 + ((kp * 4) ^ ((n & 7) << 4));
        *(unsigned*)(smem + off) = cv.u;
    }
    // ---- zero h buffers (16 KB) ----
    {
        unsigned* hz = (unsigned*)(smem + 131072);
        #pragma unroll
        for (int i = 0; i < 8; ++i) hz[tid + i * 512] = 0u;
    }

    // ---- per-lane constants ----
    float b1c[4], b2c[4], w1v[4];
    #pragma unroll
    for (int g = 0; g < 4; ++g) {
        int n = g * 128 + w * 16 + r;
        b1c[g] = bih1[n] + bhh1[n];
        b2c[g] = bih2[n] + bhh2[n];
        w1v[g] = Wih1[n];
    }
    const float wlv = Wl[w * 16 + r];
    const float bl0 = bl[0];

    // ---- Wih2 / Whh2 register B-fragments ----
    f16x8 w2i[4][4], w2h[4][4];
    #pragma unroll
    for (int g = 0; g < 4; ++g) {
        int n = g * 128 + w * 16 + r;
        #pragma unroll
        for (int kt = 0; kt < 4; ++kt) {
            int k0 = kt * 32 + q * 8;
            const float4* pi = (const float4*)(Wih2 + n * 128 + k0);
            const float4* ph = (const float4*)(Whh2 + n * 128 + k0);
            float4 ai = pi[0], bi = pi[1];
            float4 ah = ph[0], bh = ph[1];
            f16x8 vi = { (f16)ai.x,(f16)ai.y,(f16)ai.z,(f16)ai.w,
                         (f16)bi.x,(f16)bi.y,(f16)bi.z,(f16)bi.w };
            f16x8 vh = { (f16)ah.x,(f16)ah.y,(f16)ah.z,(f16)ah.w,
                         (f16)bh.x,(f16)bh.y,(f16)bh.z,(f16)bh.w };
            w2i[g][kt] = vi;
            w2h[g][kt] = vh;
        }
    }

    // A-fragment byte offsets within an h-buffer (row r, k-chunk = 32kt+8q)
    int afrag_off[4];
    #pragma unroll
    for (int kt = 0; kt < 4; ++kt)
        afrag_off[kt] = r * 256 + ((kt * 64 + q * 16) ^ ((r & 7) << 4));
    // h write offsets: element (m = 4q+i, j = 16w+r)
    int hw_off[4];
    #pragma unroll
    for (int i = 0; i < 4; ++i) {
        int m = q * 4 + i;
        hw_off[i] = m * 256 + ((w * 32 + r * 2) ^ ((m & 7) << 4));
    }

    float c1[4] = {0.f,0.f,0.f,0.f};
    float c2[4] = {0.f,0.f,0.f,0.f};
    float h2fin[4] = {0.f,0.f,0.f,0.f};

    __syncthreads();

    char* h1base = smem + 131072;
    char* h2base = smem + 131072 + 8192;

    for (int t = 0; t < TT; ++t) {
        const int p = t & 1;
        char* h1r = h1base + p * 4096;
        char* h1w = h1base + (p ^ 1) * 4096;
        char* h2r = h2base + p * 4096;
        char* h2w = h2base + (p ^ 1) * 4096;

        // x for this step's 4 rows (consumed after MFMA -> latency hidden)
        float xv[4];
        #pragma unroll
        for (int i = 0; i < 4; ++i)
            xv[i] = x[(rowbase + q * 4 + i) * TT + t];

        // ---- layer 1: gates1 = h1_prev @ Whh1^T ----
        f16x8 a1[4];
        #pragma unroll
        for (int kt = 0; kt < 4; ++kt)
            a1[kt] = *(const f16x8*)(h1r + afrag_off[kt]);

        f32x4 acc[4];
        #pragma unroll
        for (int g = 0; g < 4; ++g) {
            f32x4 a = {0.f,0.f,0.f,0.f};
            int nbase = (g * 128 + w * 16 + r) * 256;
            #pragma unroll
            for (int kt = 0; kt < 4; ++kt) {
                int boff = nbase + ((kt * 64 + q * 16) ^ ((r & 7) << 4));
                f16x8 bfr = *(const f16x8*)(smem + boff);
                a = __builtin_amdgcn_mfma_f32_16x16x32_f16(a1[kt], bfr, a, 0, 0, 0);
            }
            acc[g] = a;
        }

        // ---- layer 1 nonlinearity, c1/h1 update ----
        #pragma unroll
        for (int i = 0; i < 4; ++i) {
            float gi = sigm (acc[0][i] + b1c[0] + xv[i] * w1v[0]);
            float gf = sigm (acc[1][i] + b1c[1] + xv[i] * w1v[1]);
            float gg = tanhf_(acc[2][i] + b1c[2] + xv[i] * w1v[2]);
            float go = sigm (acc[3][i] + b1c[3] + xv[i] * w1v[3]);
            c1[i] = gf * c1[i] + gi * gg;
            float h1v = go * tanhf_(c1[i]);
            *(f16*)(h1w + hw_off[i]) = (f16)h1v;
        }

        __syncthreads();   // h1_t visible to all waves

        // ---- layer 2: gates2 = h1_t @ Wih2^T + h2_prev @ Whh2^T ----
        f16x8 ah1[4], ah2[4];
        #pragma unroll
        for (int kt = 0; kt < 4; ++kt) {
            ah1[kt] = *(const f16x8*)(h1w + afrag_off[kt]);
            ah2[kt] = *(const f16x8*)(h2r + afrag_off[kt]);
        }
        #pragma unroll
        for (int g = 0; g < 4; ++g) {
            f32x4 a = {0.f,0.f,0.f,0.f};
            #pragma unroll
            for (int kt = 0; kt < 4; ++kt)
                a = __builtin_amdgcn_mfma_f32_16x16x32_f16(ah1[kt], w2i[g][kt], a, 0, 0, 0);
            #pragma unroll
            for (int kt = 0; kt < 4; ++kt)
                a = __builtin_amdgcn_mfma_f32_16x16x32_f16(ah2[kt], w2h[g][kt], a, 0, 0, 0);
            acc[g] = a;
        }
        #pragma unroll
        for (int i = 0; i < 4; ++i) {
            float gi = sigm (acc[0][i] + b2c[0]);
            float gf = sigm (acc[1][i] + b2c[1]);
            float gg = tanhf_(acc[2][i] + b2c[2]);
            float go = sigm (acc[3][i] + b2c[3]);
            c2[i] = gf * c2[i] + gi * gg;
            float h2v = go * tanhf_(c2[i]);
            h2fin[i] = h2v;
            *(f16*)(h2w + hw_off[i]) = (f16)h2v;
        }
        // no barrier needed here: next step's mid-step barrier orders all hazards
    }

    __syncthreads();   // everyone done with Whh1 region -> reuse as reduce scratch

    // ---- out = h2_final @ Wl^T + bl (fp32) ----
    float* red = (float*)smem;           // [16][128]
    #pragma unroll
    for (int i = 0; i < 4; ++i)
        red[(q * 4 + i) * 128 + w * 16 + r] = h2fin[i] * wlv;
    __syncthreads();
    float* red2 = red + 2048;            // [16][8]
    if (tid < 128) {
        int m = tid >> 3, s = tid & 7;
        float a = 0.f;
        #pragma unroll
        for (int j = 0; j < 16; ++j) a += red[m * 128 + s * 16 + j];
        red2[m * 8 + s] = a;
    }
    __syncthreads();
    if (tid < 16) {
        float a = bl0;
        #pragma unroll
        for (int s = 0; s < 8; ++s) a += red2[tid * 8 + s];
        out[rowbase + tid] = a;
    }
}

extern "C" void kernel_launch(void* const* d_in, const int* in_sizes, int n_in,
                              void* d_out, int out_size, void* d_ws, size_t ws_size,
                              hipStream_t stream) {
    const float* x    = (const float*)d_in[0];
    const float* Wih1 = (const float*)d_in[1];
    const float* Whh1 = (const float*)d_in[2];
    const float* bih1 = (const float*)d_in[3];
    const float* bhh1 = (const float*)d_in[4];
    const float* Wih2 = (const float*)d_in[5];
    const float* Whh2 = (const float*)d_in[6];
    const float* bih2 = (const float*)d_in[7];
    const float* bhh2 = (const float*)d_in[8];
    const float* Wl   = (const float*)d_in[9];
    const float* bl   = (const float*)d_in[10];
    float* out = (float*)d_out;

    static constexpr size_t SMEM = 131072 + 16384;  // 147456 B
    hipFuncSetAttribute(reinterpret_cast<const void*>(&lstm2_fused),
                        hipFuncAttributeMaxDynamicSharedMemorySize, (int)SMEM);

    lstm2_fused<<<dim3(64), dim3(512), SMEM, stream>>>(
        x, Wih1, Whh1, bih1, bhh1, Wih2, Whh2, bih2, bhh2, Wl, bl, out);
}

// Round 4
// 887.693 us; speedup vs baseline: 1.1695x; 1.1695x over previous
//
#include <hip/hip_runtime.h>
#include <hip/hip_fp16.h>

// B=1024, T=512, H=128, G=4H=512, IN=1
#define TT 512
#define RR 4    // rows per block -> 256 blocks, all 256 CUs busy

using f16   = _Float16;
using f16x8 = __attribute__((ext_vector_type(8))) _Float16;
using f32x4 = __attribute__((ext_vector_type(4))) float;

__device__ __forceinline__ float sigm(float x) {
    return __builtin_amdgcn_rcpf(1.0f + __builtin_amdgcn_exp2f(x * -1.44269504f));
}
__device__ __forceinline__ float tanh_(float x) {
    return 1.0f - 2.0f * __builtin_amdgcn_rcpf(1.0f + __builtin_amdgcn_exp2f(x * 2.88539008f));
}

// LDS (static 24576 B):
//   [0,8192)       h1 double buffer: 2 x [16 rows][256 B] f16, chunk-swizzled
//   [8192,16384)   h2 double buffer
//   [16384,24576)  per-wave gather strips: wave w at 16384 + w*1024,
//                  gate g at +g*256, [16 cols][4 rows] f32 (b128 per col)
__global__ __launch_bounds__(512, 2) void lstm2_fused(
    const float* __restrict__ x,
    const float* __restrict__ Wih1,
    const float* __restrict__ Whh1,
    const float* __restrict__ bih1,
    const float* __restrict__ bhh1,
    const float* __restrict__ Wih2,
    const float* __restrict__ Whh2,
    const float* __restrict__ bih2,
    const float* __restrict__ bhh2,
    const float* __restrict__ Wl,
    const float* __restrict__ bl,
    float* __restrict__ out)
{
    __shared__ char smem[24576];

    const int tid  = threadIdx.x;
    const int w    = tid >> 6;      // wave 0..7 -> gate-col slice [16w,16w+16)
    const int lane = tid & 63;
    const int r    = lane & 15;     // MFMA col index / owner j-offset
    const int q    = lane >> 4;     // MFMA k-group / owner row m = q (0..3)
    const int rowbase = blockIdx.x * RR;

    // ---- zero h buffers (16 KB; rows 4..15 stay zero forever) ----
    {
        unsigned* hz = (unsigned*)smem;
        #pragma unroll
        for (int i = 0; i < 8; ++i) hz[tid + i * 512] = 0u;
    }

    // ---- owner constants: this thread owns (m = q, j = 16w + r) ----
    float b1o[4], b2o[4], w1o[4];
    #pragma unroll
    for (int g = 0; g < 4; ++g) {
        int n = g * 128 + w * 16 + r;
        b1o[g] = bih1[n] + bhh1[n];
        b2o[g] = bih2[n] + bhh2[n];
        w1o[g] = Wih1[n];
    }
    const float wlv = Wl[w * 16 + r];
    const float bl0 = bl[0];

    // ---- weight B-fragments in registers (192 VGPRs) ----
    // B-frag for mfma_16x16x32_f16: col = lane&15 = r -> n = g*128+16w+r,
    // k = kt*32 + q*8 + e
    f16x8 wr1[4][4], w2i[4][4], w2h[4][4];
    #pragma unroll
    for (int g = 0; g < 4; ++g) {
        int n = g * 128 + w * 16 + r;
        #pragma unroll
        for (int kt = 0; kt < 4; ++kt) {
            int k0 = kt * 32 + q * 8;
            const float4* p1 = (const float4*)(Whh1 + n * 128 + k0);
            const float4* pi = (const float4*)(Wih2 + n * 128 + k0);
            const float4* ph = (const float4*)(Whh2 + n * 128 + k0);
            float4 a1v = p1[0], b1v = p1[1];
            float4 ai = pi[0], bi = pi[1];
            float4 ah = ph[0], bh = ph[1];
            wr1[g][kt] = f16x8{ (f16)a1v.x,(f16)a1v.y,(f16)a1v.z,(f16)a1v.w,
                                (f16)b1v.x,(f16)b1v.y,(f16)b1v.z,(f16)b1v.w };
            w2i[g][kt] = f16x8{ (f16)ai.x,(f16)ai.y,(f16)ai.z,(f16)ai.w,
                                (f16)bi.x,(f16)bi.y,(f16)bi.z,(f16)bi.w };
            w2h[g][kt] = f16x8{ (f16)ah.x,(f16)ah.y,(f16)ah.z,(f16)ah.w,
                                (f16)bh.x,(f16)bh.y,(f16)bh.z,(f16)bh.w };
        }
    }

    // A-fragment byte offsets (row = r, k-chunk = 32kt + 8q), chunk-swizzled
    int afrag[4];
    #pragma unroll
    for (int kt = 0; kt < 4; ++kt)
        afrag[kt] = r * 256 + ((kt * 64 + q * 16) ^ ((r & 7) << 4));
    // owner h-write offset: row m=q (<4), col j=16w+r -> q*256 + (2j ^ (q<<4))
    const int hwoff = q * 256 + ((w * 32 + r * 2) ^ (q << 4));
    // gather strip addresses (intra-wave only)
    char* const gbase = smem + 16384 + w * 1024;

    float c1 = 0.f, c2 = 0.f, h2fin = 0.f;

    __syncthreads();

    char* const h1base = smem;
    char* const h2base = smem + 8192;

    for (int t = 0; t < TT; ++t) {
        const int p = t & 1;
        char* h1r = h1base + p * 4096;
        char* h1w = h1base + (p ^ 1) * 4096;
        char* h2r = h2base + p * 4096;
        char* h2w = h2base + (p ^ 1) * 4096;

        // owner's x value for this step (issued early; used mid-phase)
        const float xv = x[(rowbase + q) * TT + t];

        // ---- layer 1: gates1 = h1_prev @ Whh1^T ----
        f32x4 acc[4] = {{0.f,0.f,0.f,0.f},{0.f,0.f,0.f,0.f},
                        {0.f,0.f,0.f,0.f},{0.f,0.f,0.f,0.f}};
        #pragma unroll
        for (int kt = 0; kt < 4; ++kt) {
            f16x8 a1 = *(const f16x8*)(h1r + afrag[kt]);
            #pragma unroll
            for (int g = 0; g < 4; ++g)
                acc[g] = __builtin_amdgcn_mfma_f32_16x16x32_f16(a1, wr1[g][kt], acc[g], 0, 0, 0);
        }
        // redistribute: q==0 lanes hold all 4 real rows (regs 0..3) for col r
        if (q == 0) {
            #pragma unroll
            for (int g = 0; g < 4; ++g)
                *(f32x4*)(gbase + g * 256 + r * 16) = acc[g];
        }
        // every lane: its (m=q, j=16w+r) pre-activations; gate math (all lanes real)
        {
            float pre[4];
            #pragma unroll
            for (int g = 0; g < 4; ++g)
                pre[g] = ((const float*)(gbase + g * 256 + r * 16))[q]
                         + fmaf(xv, w1o[g], b1o[g]);
            float gi = sigm (pre[0]);
            float gf = sigm (pre[1]);
            float gg = tanh_(pre[2]);
            float go = sigm (pre[3]);
            c1 = gf * c1 + gi * gg;
            float h1v = go * tanh_(c1);
            *(f16*)(h1w + hwoff) = (f16)h1v;
        }

        __syncthreads();   // h1_t visible to all waves

        // ---- layer 2: gates2 = h1_t @ Wih2^T + h2_prev @ Whh2^T ----
        f32x4 acc2[4] = {{0.f,0.f,0.f,0.f},{0.f,0.f,0.f,0.f},
                         {0.f,0.f,0.f,0.f},{0.f,0.f,0.f,0.f}};
        #pragma unroll
        for (int kt = 0; kt < 4; ++kt) {
            f16x8 ah1 = *(const f16x8*)(h1w + afrag[kt]);
            f16x8 ah2 = *(const f16x8*)(h2r + afrag[kt]);
            #pragma unroll
            for (int g = 0; g < 4; ++g)
                acc2[g] = __builtin_amdgcn_mfma_f32_16x16x32_f16(ah1, w2i[g][kt], acc2[g], 0, 0, 0);
            #pragma unroll
            for (int g = 0; g < 4; ++g)
                acc2[g] = __builtin_amdgcn_mfma_f32_16x16x32_f16(ah2, w2h[g][kt], acc2[g], 0, 0, 0);
        }
        if (q == 0) {
            #pragma unroll
            for (int g = 0; g < 4; ++g)
                *(f32x4*)(gbase + g * 256 + r * 16) = acc2[g];
        }
        {
            float pre[4];
            #pragma unroll
            for (int g = 0; g < 4; ++g)
                pre[g] = ((const float*)(gbase + g * 256 + r * 16))[q] + b2o[g];
            float gi = sigm (pre[0]);
            float gf = sigm (pre[1]);
            float gg = tanh_(pre[2]);
            float go = sigm (pre[3]);
            c2 = gf * c2 + gi * gg;
            float h2v = go * tanh_(c2);
            h2fin = h2v;
            *(f16*)(h2w + hwoff) = (f16)h2v;
        }

        __syncthreads();   // end-of-step (defensive: closes all WAR/RAW windows)
    }

    // ---- out[m] = sum_j h2[m][j] * Wl[j] + bl, m = 0..3 ----
    float v = h2fin * wlv;               // owner (m=q, j=16w+r)
    v += __shfl_xor(v, 1);
    v += __shfl_xor(v, 2);
    v += __shfl_xor(v, 4);
    v += __shfl_xor(v, 8);               // lanes q*16 hold wave-partial for row q
    float* red = (float*)(smem + 16384); // 32 floats: [q][w]
    if (r == 0) red[q * 8 + w] = v;
    __syncthreads();
    if (tid < RR) {
        float a = bl0;
        #pragma unroll
        for (int s = 0; s < 8; ++s) a += red[tid * 8 + s];
        out[rowbase + tid] = a;
    }
}

extern "C" void kernel_launch(void* const* d_in, const int* in_sizes, int n_in,
                              void* d_out, int out_size, void* d_ws, size_t ws_size,
                              hipStream_t stream) {
    const float* x    = (const float*)d_in[0];
    const float* Wih1 = (const float*)d_in[1];
    const float* Whh1 = (const float*)d_in[2];
    const float* bih1 = (const float*)d_in[3];
    const float* bhh1 = (const float*)d_in[4];
    const float* Wih2 = (const float*)d_in[5];
    const float* Whh2 = (const float*)d_in[6];
    const float* bih2 = (const float*)d_in[7];
    const float* bhh2 = (const float*)d_in[8];
    const float* Wl   = (const float*)d_in[9];
    const float* bl   = (const float*)d_in[10];
    float* out = (float*)d_out;

    lstm2_fused<<<dim3(256), dim3(512), 0, stream>>>(
        x, Wih1, Whh1, bih1, bhh1, Wih2, Whh2, bih2, bhh2, Wl, bl, out);
}